// Round 8
// baseline (244.112 us; speedup 1.0000x reference)
//
#include <hip/hip_runtime.h>

#define N_NODES 10000
#define N_EDGES 640000
#define CH 128
#define NHB 128              // hist/scatter edge partitions
#define EPB (N_EDGES / NHB)  // 5000 edges per partition
#define NCHUNK 40            // ceil(N_NODES/256)
#define GT 157               // ceil(N_NODES/64) gemm tiles

// ---------------------------------------------------------------------------
// GEMM tile: out[m][o] = sum_k A[m][k] * W[o][k]; 64 rows x 128 cols per tile.
__device__ __forceinline__ void gemm_tile(const float* __restrict__ A,
        const float* __restrict__ W, float* __restrict__ out, int tile,
        float (*As)[68], float (*Ws)[132]) {
    int tid = threadIdx.x;
    int tx = tid & 31;
    int ty = tid >> 5;
    int row0 = tile * 64;
    float acc[8][4] = {};
    for (int k0 = 0; k0 < 128; k0 += 32) {
        #pragma unroll
        for (int i = 0; i < 8; ++i) {
            int idx = tid + i * 256;
            int r = idx >> 5, k = idx & 31;
            int gr = row0 + r;
            As[k][r] = (gr < N_NODES) ? A[gr * CH + k0 + k] : 0.0f;
        }
        #pragma unroll
        for (int i = 0; i < 16; ++i) {
            int idx = tid + i * 256;
            int o = idx >> 5, k = idx & 31;
            Ws[k][o] = W[o * CH + k0 + k];
        }
        __syncthreads();
        #pragma unroll
        for (int kk = 0; kk < 32; ++kk) {
            float a[8], w[4];
            #pragma unroll
            for (int j = 0; j < 8; ++j) a[j] = As[kk][ty * 8 + j];
            #pragma unroll
            for (int c = 0; c < 4; ++c) w[c] = Ws[kk][tx * 4 + c];
            #pragma unroll
            for (int j = 0; j < 8; ++j)
                #pragma unroll
                for (int c = 0; c < 4; ++c)
                    acc[j][c] += a[j] * w[c];
        }
        __syncthreads();
    }
    #pragma unroll
    for (int j = 0; j < 8; ++j) {
        int gr = row0 + ty * 8 + j;
        if (gr < N_NODES) {
            float4 v = make_float4(acc[j][0], acc[j][1], acc[j][2], acc[j][3]);
            *reinterpret_cast<float4*>(&out[gr * CH + tx * 4]) = v;
        }
    }
}

// ---------------------------------------------------------------------------
// Launch 1: blocks 0..127 = hist (+ per-chunk sums); 128..284 = gemm1 tiles;
// 285 = conv1d+fc weight folding. No shared data between the three roles.
__global__ __launch_bounds__(256) void build1_kernel(
        const float* __restrict__ x, const int* __restrict__ ei,
        const float* __restrict__ ew, const float* __restrict__ W1,
        const float* __restrict__ conv_w, const float* __restrict__ conv_b,
        const float* __restrict__ fc_w, const float* __restrict__ fc_b,
        float* __restrict__ xw1, int* __restrict__ hist, float* __restrict__ dhist,
        int* __restrict__ chunk_sum, float* __restrict__ vbuf, float* __restrict__ c0) {
    __shared__ union {
        struct { int h[N_NODES]; float hf[N_NODES]; } hist;     // 80 KB
        struct { float As[32][68]; float Ws[32][132]; } gemm;   // ~26 KB
    } sm;
    __shared__ int wred[4];
    const int b = blockIdx.x, t = threadIdx.x;

    if (b < NHB) {
        // ---- histogram: count + weighted degree, LDS atomics only ----
        for (int i = t; i < N_NODES; i += 256) { sm.hist.h[i] = 0; sm.hist.hf[i] = 0.0f; }
        __syncthreads();
        int e0 = b * EPB;
        for (int i = t; i < EPB; i += 256) {
            int c = ei[N_EDGES + e0 + i];
            float w = ew[e0 + i];
            atomicAdd(&sm.hist.h[c], 1);
            atomicAdd(&sm.hist.hf[c], w);
        }
        __syncthreads();
        // flush + per-256-node-chunk sums (chunk j == flush iteration j)
        int lane = t & 63, wave = t >> 6;
        for (int j = 0; j < NCHUNK; ++j) {
            int i = j * 256 + t;
            int val = 0;
            if (i < N_NODES) {
                val = sm.hist.h[i];
                hist[b * N_NODES + i] = val;
                dhist[b * N_NODES + i] = sm.hist.hf[i];
            }
            int s = val;
            #pragma unroll
            for (int off = 32; off > 0; off >>= 1) s += __shfl_down(s, off, 64);
            if (lane == 0) wred[wave] = s;
            __syncthreads();
            if (t == 0) chunk_sum[j * NHB + b] = wred[0] + wred[1] + wred[2] + wred[3];
            __syncthreads();
        }
    } else if (b < NHB + GT) {
        gemm_tile(x, W1, xw1, b - NHB, sm.gemm.As, sm.gemm.Ws);
    } else {
        // ---- conv1d(k=3)+FC weight folding: v[i][k] = sum_o fc_w[o]*conv_w[o][i][k] ----
        for (int i = t; i <= 384; i += 256) {
            if (i < 384) {
                float s = 0.0f;
                for (int o = 0; o < CH; ++o) s += fc_w[o] * conv_w[o * 384 + i];
                vbuf[i] = s;
            } else {
                float s = fc_b[0];
                for (int o = 0; o < CH; ++o) s += fc_w[o] * conv_b[o];
                *c0 = s;
            }
        }
    }
}

// ---------------------------------------------------------------------------
// Launch 2: merged reduce + scan + cursor conversion. 40 blocks.
// base for chunk blk = sum of chunk_sum[j][*] for j < blk  (5120 ints, L2-hot).
__global__ __launch_bounds__(256) void reducebofs_kernel(int* __restrict__ hist,
        const float* __restrict__ dhist, const int* __restrict__ chunk_sum,
        int* __restrict__ tot, int* __restrict__ offs, float* __restrict__ dinv) {
    __shared__ int wred[4];
    __shared__ int wsum[4];
    __shared__ int base_s;
    const int blk = blockIdx.x, t = threadIdx.x;
    const int lane = t & 63, wave = t >> 6;

    // (a) global base from chunk sums
    int part = 0;
    for (int idx = t; idx < NCHUNK * NHB; idx += 256) {
        int j = idx >> 7;                      // NHB = 128
        if (j < blk) part += chunk_sum[idx];
    }
    int s = part;
    #pragma unroll
    for (int off = 32; off > 0; off >>= 1) s += __shfl_down(s, off, 64);
    if (lane == 0) wred[wave] = s;
    __syncthreads();
    if (t == 0) base_s = wred[0] + wred[1] + wred[2] + wred[3];

    // (b) own column reduce -> tot, dinv
    int n = blk * 256 + t;
    int c = 0;
    if (n < N_NODES) {
        float d = 0.0f;
        #pragma unroll 4
        for (int bb = 0; bb < NHB; ++bb) {
            c += hist[bb * N_NODES + n];
            d += dhist[bb * N_NODES + n];
        }
        tot[n] = c;
        dinv[n] = rsqrtf(d + 1.0f);            // +1 = self-loop weight
    }
    // (c) local inclusive scan of the chunk's 256 counts
    s = c;
    #pragma unroll
    for (int off = 1; off < 64; off <<= 1) {
        int u = __shfl_up(s, off, 64);
        if (lane >= off) s += u;
    }
    if (lane == 63) wsum[wave] = s;
    __syncthreads();
    int wbase = 0;
    for (int i = 0; i < wave; ++i) wbase += wsum[i];
    // (d) offs + per-(block,node) start cursors (hist in-place)
    if (n < N_NODES) {
        int run = base_s + wbase + s - c;      // global exclusive prefix
        offs[n] = run;
        for (int bb = 0; bb < NHB; ++bb) {
            int hh = hist[bb * N_NODES + n];
            hist[bb * N_NODES + n] = run;
            run += hh;
        }
    }
}

// ---------------------------------------------------------------------------
// Launch 3: scatter edges into CSR order; packed {src, val} 8B records.
__global__ __launch_bounds__(256) void scatter_kernel(const int* __restrict__ ei,
        const float* __restrict__ ew, const float* __restrict__ dinv,
        const int* __restrict__ bofs, int2* __restrict__ erec) {
    __shared__ int cur[N_NODES];               // 40 KB
    __shared__ float di[N_NODES];              // 40 KB
    int b = blockIdx.x, t = threadIdx.x;
    for (int i = t; i < N_NODES; i += 256) {
        cur[i] = bofs[b * N_NODES + i];
        di[i] = dinv[i];
    }
    __syncthreads();
    int e0 = b * EPB;
    for (int i = t; i < EPB; i += 256) {
        int e = e0 + i;
        int r = ei[e];
        int c = ei[N_EDGES + e];
        int p = atomicAdd(&cur[c], 1);         // LDS atomic
        float v = di[r] * ew[e] * di[c];
        erec[p] = make_int2(r, __float_as_int(v));
    }
}

// ---------------------------------------------------------------------------
// Standalone GEMM for layer 2.
__global__ __launch_bounds__(256) void gemm128_kernel(const float* __restrict__ A,
                                                      const float* __restrict__ W,
                                                      float* __restrict__ out) {
    __shared__ float As[32][68];
    __shared__ float Ws[32][132];
    gemm_tile(A, W, out, blockIdx.x, As, Ws);
}

// ---------------------------------------------------------------------------
// Aggregation: 32 lanes per node (float4/lane), 8 nodes/block, unroll x8.
__global__ __launch_bounds__(256) void agg_kernel(const float4* __restrict__ xw4,
        const int2* __restrict__ erec, const int* __restrict__ offs,
        const int* __restrict__ cnt, const float* __restrict__ dinv,
        const float4* __restrict__ bias4, float4* __restrict__ out4) {
    int l = threadIdx.x & 31;                  // channel quad
    int g = threadIdx.x >> 5;                  // node group 0..7
    int n = blockIdx.x * 8 + g;                // grid = 1250 -> n < 10000 always
    float d = dinv[n];
    float dd = d * d;
    float4 self = xw4[n * 32 + l];
    float4 acc = make_float4(dd * self.x, dd * self.y, dd * self.z, dd * self.w);
    int start = offs[n];
    int num = cnt[n];
    int i = 0;
    for (; i + 8 <= num; i += 8) {
        int2 r[8];
        #pragma unroll
        for (int j = 0; j < 8; ++j) r[j] = erec[start + i + j];
        float4 f[8];
        #pragma unroll
        for (int j = 0; j < 8; ++j) f[j] = xw4[r[j].x * 32 + l];
        #pragma unroll
        for (int j = 0; j < 8; ++j) {
            float v = __int_as_float(r[j].y);
            acc.x += v * f[j].x; acc.y += v * f[j].y;
            acc.z += v * f[j].z; acc.w += v * f[j].w;
        }
    }
    for (; i < num; ++i) {
        int2 r = erec[start + i];
        float4 f = xw4[r.x * 32 + l];
        float v = __int_as_float(r.y);
        acc.x += v * f.x; acc.y += v * f.y; acc.z += v * f.z; acc.w += v * f.w;
    }
    float4 bb = bias4[l];
    acc.x = fmaxf(acc.x + bb.x, 0.0f);
    acc.y = fmaxf(acc.y + bb.y, 0.0f);
    acc.z = fmaxf(acc.z + bb.z, 0.0f);
    acc.w = fmaxf(acc.w + bb.w, 0.0f);
    out4[n * 32 + l] = acc;
}

// ---------------------------------------------------------------------------
// Fused temporal conv(k=3) + FC: 32 lanes/node, float4 loads, 8 nodes/block.
__global__ __launch_bounds__(256) void convfc_kernel(const float4* __restrict__ h4,
        const float* __restrict__ vbuf, const float* __restrict__ c0,
        float* __restrict__ out) {
    int l = threadIdx.x & 31;
    int g = threadIdx.x >> 5;
    int n = blockIdx.x * 8 + g;                // grid = 1250
    float v00 = vbuf[(4 * l + 0) * 3 + 0], v01 = vbuf[(4 * l + 0) * 3 + 1], v02 = vbuf[(4 * l + 0) * 3 + 2];
    float v10 = vbuf[(4 * l + 1) * 3 + 0], v11 = vbuf[(4 * l + 1) * 3 + 1], v12 = vbuf[(4 * l + 1) * 3 + 2];
    float v20 = vbuf[(4 * l + 2) * 3 + 0], v21 = vbuf[(4 * l + 2) * 3 + 1], v22 = vbuf[(4 * l + 2) * 3 + 2];
    float v30 = vbuf[(4 * l + 3) * 3 + 0], v31 = vbuf[(4 * l + 3) * 3 + 1], v32 = vbuf[(4 * l + 3) * 3 + 2];
    float4 hm = h4[n * 32 + l];
    float p = hm.x * v01 + hm.y * v11 + hm.z * v21 + hm.w * v31;
    if (n > 0) {
        float4 ha = h4[(n - 1) * 32 + l];
        p += ha.x * v00 + ha.y * v10 + ha.z * v20 + ha.w * v30;
    }
    if (n < N_NODES - 1) {
        float4 hb = h4[(n + 1) * 32 + l];
        p += hb.x * v02 + hb.y * v12 + hb.z * v22 + hb.w * v32;
    }
    #pragma unroll
    for (int off = 16; off > 0; off >>= 1) p += __shfl_down(p, off, 32);
    if (l == 0) out[n] = p + *c0;
}

// ---------------------------------------------------------------------------
extern "C" void kernel_launch(void* const* d_in, const int* in_sizes, int n_in,
                              void* d_out, int out_size, void* d_ws, size_t ws_size,
                              hipStream_t stream) {
    const float* x       = (const float*)d_in[0];
    const int*   ei      = (const int*)d_in[1];
    const float* ew      = (const float*)d_in[2];
    const float* W1      = (const float*)d_in[3];
    const float* b1      = (const float*)d_in[4];
    const float* W2      = (const float*)d_in[5];
    const float* b2      = (const float*)d_in[6];
    const float* conv_w  = (const float*)d_in[7];
    const float* conv_b  = (const float*)d_in[8];
    const float* fc_w    = (const float*)d_in[9];
    const float* fc_b    = (const float*)d_in[10];
    float* out = (float*)d_out;

    // Workspace: fully de-aliased (gemm1 runs concurrently with hist). ~31 MB.
    float* xw1    = (float*)d_ws;                   // 1,280,000 f
    float* bufB   = xw1 + N_NODES * CH;             // 1,280,000 f  (h1, then h2)
    float* xw2    = bufB + N_NODES * CH;            // 1,280,000 f
    int2*  erec   = (int2*)(xw2 + N_NODES * CH);    // 640,000 x 8B
    int*   hist   = (int*)(erec + N_EDGES);         // NHB*10,000 i
    float* dhist  = (float*)(hist + NHB * N_NODES); // NHB*10,000 f
    int*   chunks = (int*)(dhist + NHB * N_NODES);  // NCHUNK*NHB i
    int*   tot    = chunks + NCHUNK * NHB;          // 10,000 i
    int*   offs   = tot + N_NODES;                  // 10,000 i
    float* dinv   = (float*)(offs + N_NODES);       // 10,000 f
    float* vbuf   = dinv + N_NODES;                 // 384 f
    float* c0     = vbuf + 384;                     // 1 f

    // --- launch 1: hist || gemm1 || conv-fold ---
    build1_kernel<<<NHB + GT + 1, 256, 0, stream>>>(x, ei, ew, W1, conv_w, conv_b,
                                                    fc_w, fc_b, xw1, hist, dhist,
                                                    chunks, vbuf, c0);
    // --- launch 2: reduce + scan + cursors ---
    reducebofs_kernel<<<NCHUNK, 256, 0, stream>>>(hist, dhist, chunks, tot, offs, dinv);
    // --- launch 3: scatter into CSR records ---
    scatter_kernel<<<NHB, 256, 0, stream>>>(ei, ew, dinv, hist, erec);
    // --- launch 4: layer-1 aggregation ---
    agg_kernel<<<N_NODES / 8, 256, 0, stream>>>((const float4*)xw1, erec, offs, tot,
                                                dinv, (const float4*)b1, (float4*)bufB);
    // --- launch 5: gemm2 ---
    gemm128_kernel<<<GT, 256, 0, stream>>>(bufB, W2, xw2);
    // --- launch 6: layer-2 aggregation ---
    agg_kernel<<<N_NODES / 8, 256, 0, stream>>>((const float4*)xw2, erec, offs, tot,
                                                dinv, (const float4*)b2, (float4*)bufB);
    // --- launch 7: fused temporal conv + fc ---
    convfc_kernel<<<N_NODES / 8, 256, 0, stream>>>((const float4*)bufB, vbuf, c0, out);
}

// Round 9
// 241.366 us; speedup vs baseline: 1.0114x; 1.0114x over previous
//
#include <hip/hip_runtime.h>

#define N_NODES 10000
#define N_EDGES 640000
#define CH 128
#define NHB 128              // hist/scatter edge partitions
#define EPB (N_EDGES / NHB)  // 5000 edges per partition
#define NCHUNK 40            // ceil(N_NODES/256)
#define GT 157               // ceil(N_NODES/64) gemm tiles

// ---------------------------------------------------------------------------
// GEMM tile: out[m][o] = sum_k A[m][k] * W[o][k]; 64 rows x 128 cols per tile.
__device__ __forceinline__ void gemm_tile(const float* __restrict__ A,
        const float* __restrict__ W, float* __restrict__ out, int tile,
        float (*As)[68], float (*Ws)[132]) {
    int tid = threadIdx.x;
    int tx = tid & 31;
    int ty = tid >> 5;
    int row0 = tile * 64;
    float acc[8][4] = {};
    for (int k0 = 0; k0 < 128; k0 += 32) {
        #pragma unroll
        for (int i = 0; i < 8; ++i) {
            int idx = tid + i * 256;
            int r = idx >> 5, k = idx & 31;
            int gr = row0 + r;
            As[k][r] = (gr < N_NODES) ? A[gr * CH + k0 + k] : 0.0f;
        }
        #pragma unroll
        for (int i = 0; i < 16; ++i) {
            int idx = tid + i * 256;
            int o = idx >> 5, k = idx & 31;
            Ws[k][o] = W[o * CH + k0 + k];
        }
        __syncthreads();
        #pragma unroll
        for (int kk = 0; kk < 32; ++kk) {
            float a[8], w[4];
            #pragma unroll
            for (int j = 0; j < 8; ++j) a[j] = As[kk][ty * 8 + j];
            #pragma unroll
            for (int c = 0; c < 4; ++c) w[c] = Ws[kk][tx * 4 + c];
            #pragma unroll
            for (int j = 0; j < 8; ++j)
                #pragma unroll
                for (int c = 0; c < 4; ++c)
                    acc[j][c] += a[j] * w[c];
        }
        __syncthreads();
    }
    #pragma unroll
    for (int j = 0; j < 8; ++j) {
        int gr = row0 + ty * 8 + j;
        if (gr < N_NODES) {
            float4 v = make_float4(acc[j][0], acc[j][1], acc[j][2], acc[j][3]);
            *reinterpret_cast<float4*>(&out[gr * CH + tx * 4]) = v;
        }
    }
}

// ---------------------------------------------------------------------------
// Launch 1: blocks 0..127 = count-hist (40 KB LDS); 128..284 = gemm1 tiles;
// 285 = conv1d+fc weight folding. LDS union is 40 KB -> up to 4 blocks/CU,
// so hist and gemm blocks co-schedule and hide each other's latency.
__global__ __launch_bounds__(256) void build1_kernel(
        const float* __restrict__ x, const int* __restrict__ ei,
        const float* __restrict__ W1,
        const float* __restrict__ conv_w, const float* __restrict__ conv_b,
        const float* __restrict__ fc_w, const float* __restrict__ fc_b,
        float* __restrict__ xw1, int* __restrict__ hist,
        int* __restrict__ chunk_sum, float* __restrict__ vbuf, float* __restrict__ c0) {
    __shared__ union {
        int h[N_NODES];                                     // 40 KB
        struct { float As[32][68]; float Ws[32][132]; } gemm;  // 25.6 KB
    } sm;
    const int b = blockIdx.x, t = threadIdx.x;

    if (b < NHB) {
        // ---- count histogram, LDS atomics only ----
        for (int i = t; i < N_NODES; i += 256) sm.h[i] = 0;
        __syncthreads();
        int e0 = b * EPB;
        for (int i = t; i < EPB; i += 256)
            atomicAdd(&sm.h[ei[N_EDGES + e0 + i]], 1);
        __syncthreads();
        // flush
        for (int i = t; i < N_NODES; i += 256) hist[b * N_NODES + i] = sm.h[i];
        // per-256-node chunk sums (wave-parallel, no extra syncs)
        int lane = t & 63, wave = t >> 6;
        for (int j = wave; j < NCHUNK; j += 4) {
            int s = 0;
            #pragma unroll
            for (int q = 0; q < 4; ++q) {
                int idx = j * 256 + q * 64 + lane;
                if (idx < N_NODES) s += sm.h[idx];
            }
            #pragma unroll
            for (int off = 32; off > 0; off >>= 1) s += __shfl_down(s, off, 64);
            if (lane == 0) chunk_sum[j * NHB + b] = s;
        }
    } else if (b < NHB + GT) {
        gemm_tile(x, W1, xw1, b - NHB, sm.gemm.As, sm.gemm.Ws);
    } else {
        // ---- conv1d(k=3)+FC weight folding ----
        for (int i = t; i <= 384; i += 256) {
            if (i < 384) {
                float s = 0.0f;
                for (int o = 0; o < CH; ++o) s += fc_w[o] * conv_w[o * 384 + i];
                vbuf[i] = s;
            } else {
                float s = fc_b[0];
                for (int o = 0; o < CH; ++o) s += fc_w[o] * conv_b[o];
                *c0 = s;
            }
        }
    }
}

// ---------------------------------------------------------------------------
// Launch 2: offs[n] = global exclusive prefix of per-node counts; hist columns
// converted in-place to per-(block,node) start cursors. offs[N_NODES] = E.
__global__ __launch_bounds__(256) void reducebofs_kernel(int* __restrict__ hist,
        const int* __restrict__ chunk_sum, int* __restrict__ offs) {
    __shared__ int wred[4];
    __shared__ int wsum[4];
    __shared__ int base_s;
    const int blk = blockIdx.x, t = threadIdx.x;
    const int lane = t & 63, wave = t >> 6;

    // (a) global base = sum of chunk_sum[j][*] for j < blk
    int part = 0;
    for (int idx = t; idx < NCHUNK * NHB; idx += 256) {
        int j = idx >> 7;                      // NHB = 128
        if (j < blk) part += chunk_sum[idx];
    }
    int s = part;
    #pragma unroll
    for (int off = 32; off > 0; off >>= 1) s += __shfl_down(s, off, 64);
    if (lane == 0) wred[wave] = s;
    __syncthreads();
    if (t == 0) base_s = wred[0] + wred[1] + wred[2] + wred[3];

    // (b) column reduce -> per-node count
    int n = blk * 256 + t;
    int c = 0;
    if (n < N_NODES) {
        #pragma unroll 4
        for (int bb = 0; bb < NHB; ++bb) c += hist[bb * N_NODES + n];
    }
    // (c) local inclusive scan of the 256 counts
    s = c;
    #pragma unroll
    for (int off = 1; off < 64; off <<= 1) {
        int u = __shfl_up(s, off, 64);
        if (lane >= off) s += u;
    }
    if (lane == 63) wsum[wave] = s;
    __syncthreads();
    int wbase = 0;
    for (int i = 0; i < wave; ++i) wbase += wsum[i];
    // (d) offs + cursor conversion
    if (n < N_NODES) {
        int run = base_s + wbase + s - c;      // global exclusive prefix
        offs[n] = run;
        #pragma unroll 4
        for (int bb = 0; bb < NHB; ++bb) {
            int hh = hist[bb * N_NODES + n];
            hist[bb * N_NODES + n] = run;
            run += hh;
        }
        if (n == N_NODES - 1) offs[N_NODES] = run;
    }
}

// ---------------------------------------------------------------------------
// Launch 3: scatter edges into CSR order; packed {src, raw_w} 8B records.
// 40 KB LDS only (cursors) -> better occupancy than the 80 KB variant.
__global__ __launch_bounds__(256) void scatter_kernel(const int* __restrict__ ei,
        const float* __restrict__ ew, const int* __restrict__ bofs,
        int2* __restrict__ erec) {
    __shared__ int cur[N_NODES];               // 40 KB
    int b = blockIdx.x, t = threadIdx.x;
    for (int i = t; i < N_NODES; i += 256) cur[i] = bofs[b * N_NODES + i];
    __syncthreads();
    int e0 = b * EPB;
    for (int i = t; i < EPB; i += 256) {
        int e = e0 + i;
        int r = ei[e];
        int c = ei[N_EDGES + e];
        int p = atomicAdd(&cur[c], 1);         // LDS atomic
        erec[p] = make_int2(r, __float_as_int(ew[e]));
    }
}

// ---------------------------------------------------------------------------
// Launch 4: weighted degree from CSR ranges -> dinv. 16 lanes per node.
__global__ __launch_bounds__(256) void degdinv_kernel(const int2* __restrict__ erec,
        const int* __restrict__ offs, float* __restrict__ dinv) {
    int sub = threadIdx.x & 15;
    int g = threadIdx.x >> 4;                  // 16 nodes per block
    int n = blockIdx.x * 16 + g;               // grid 625 -> exactly 10000
    int s0 = offs[n], s1 = offs[n + 1];
    float d = 0.0f;
    for (int i = s0 + sub; i < s1; i += 16) d += __int_as_float(erec[i].y);
    #pragma unroll
    for (int off = 8; off > 0; off >>= 1) d += __shfl_down(d, off, 16);
    if (sub == 0) dinv[n] = rsqrtf(d + 1.0f);  // +1 = self-loop weight
}

// ---------------------------------------------------------------------------
// Standalone GEMM for layer 2.
__global__ __launch_bounds__(256) void gemm128_kernel(const float* __restrict__ A,
                                                      const float* __restrict__ W,
                                                      float* __restrict__ out) {
    __shared__ float As[32][68];
    __shared__ float Ws[32][132];
    gemm_tile(A, W, out, blockIdx.x, As, Ws);
}

// ---------------------------------------------------------------------------
// Aggregation: 32 lanes/node (float4/lane), 8 nodes/block, unroll x8.
// erec = {src, raw_w}; normalization applied algebraically:
//   out = relu( dinv_n * ( sum_e dinv_r*w*row + dinv_n*self ) + bias )
__global__ __launch_bounds__(256) void agg_kernel(const float4* __restrict__ xw4,
        const int2* __restrict__ erec, const int* __restrict__ offs,
        const float* __restrict__ dinv, const float4* __restrict__ bias4,
        float4* __restrict__ out4) {
    int l = threadIdx.x & 31;                  // channel quad
    int g = threadIdx.x >> 5;                  // node group 0..7
    int n = blockIdx.x * 8 + g;                // grid = 1250
    float dn = dinv[n];
    float4 self = xw4[n * 32 + l];
    float4 acc = make_float4(dn * self.x, dn * self.y, dn * self.z, dn * self.w);
    int start = offs[n];
    int num = offs[n + 1] - start;
    int i = 0;
    for (; i + 8 <= num; i += 8) {
        int2 r[8];
        #pragma unroll
        for (int j = 0; j < 8; ++j) r[j] = erec[start + i + j];
        float dv[8];
        #pragma unroll
        for (int j = 0; j < 8; ++j) dv[j] = dinv[r[j].x];   // broadcast, L1-hot
        float4 f[8];
        #pragma unroll
        for (int j = 0; j < 8; ++j) f[j] = xw4[r[j].x * 32 + l];
        #pragma unroll
        for (int j = 0; j < 8; ++j) {
            float v = dv[j] * __int_as_float(r[j].y);
            acc.x += v * f[j].x; acc.y += v * f[j].y;
            acc.z += v * f[j].z; acc.w += v * f[j].w;
        }
    }
    for (; i < num; ++i) {
        int2 r = erec[start + i];
        float v = dinv[r.x] * __int_as_float(r.y);
        float4 f = xw4[r.x * 32 + l];
        acc.x += v * f.x; acc.y += v * f.y; acc.z += v * f.z; acc.w += v * f.w;
    }
    float4 bb = bias4[l];
    acc.x = fmaxf(dn * acc.x + bb.x, 0.0f);
    acc.y = fmaxf(dn * acc.y + bb.y, 0.0f);
    acc.z = fmaxf(dn * acc.z + bb.z, 0.0f);
    acc.w = fmaxf(dn * acc.w + bb.w, 0.0f);
    out4[n * 32 + l] = acc;
}

// ---------------------------------------------------------------------------
// Fused temporal conv(k=3) + FC: 32 lanes/node, float4 loads, 8 nodes/block.
__global__ __launch_bounds__(256) void convfc_kernel(const float4* __restrict__ h4,
        const float* __restrict__ vbuf, const float* __restrict__ c0,
        float* __restrict__ out) {
    int l = threadIdx.x & 31;
    int g = threadIdx.x >> 5;
    int n = blockIdx.x * 8 + g;                // grid = 1250
    float v00 = vbuf[(4 * l + 0) * 3 + 0], v01 = vbuf[(4 * l + 0) * 3 + 1], v02 = vbuf[(4 * l + 0) * 3 + 2];
    float v10 = vbuf[(4 * l + 1) * 3 + 0], v11 = vbuf[(4 * l + 1) * 3 + 1], v12 = vbuf[(4 * l + 1) * 3 + 2];
    float v20 = vbuf[(4 * l + 2) * 3 + 0], v21 = vbuf[(4 * l + 2) * 3 + 1], v22 = vbuf[(4 * l + 2) * 3 + 2];
    float v30 = vbuf[(4 * l + 3) * 3 + 0], v31 = vbuf[(4 * l + 3) * 3 + 1], v32 = vbuf[(4 * l + 3) * 3 + 2];
    float4 hm = h4[n * 32 + l];
    float p = hm.x * v01 + hm.y * v11 + hm.z * v21 + hm.w * v31;
    if (n > 0) {
        float4 ha = h4[(n - 1) * 32 + l];
        p += ha.x * v00 + ha.y * v10 + ha.z * v20 + ha.w * v30;
    }
    if (n < N_NODES - 1) {
        float4 hb = h4[(n + 1) * 32 + l];
        p += hb.x * v02 + hb.y * v12 + hb.z * v22 + hb.w * v32;
    }
    #pragma unroll
    for (int off = 16; off > 0; off >>= 1) p += __shfl_down(p, off, 32);
    if (l == 0) out[n] = p + *c0;
}

// ---------------------------------------------------------------------------
extern "C" void kernel_launch(void* const* d_in, const int* in_sizes, int n_in,
                              void* d_out, int out_size, void* d_ws, size_t ws_size,
                              hipStream_t stream) {
    const float* x       = (const float*)d_in[0];
    const int*   ei      = (const int*)d_in[1];
    const float* ew      = (const float*)d_in[2];
    const float* W1      = (const float*)d_in[3];
    const float* b1      = (const float*)d_in[4];
    const float* W2      = (const float*)d_in[5];
    const float* b2      = (const float*)d_in[6];
    const float* conv_w  = (const float*)d_in[7];
    const float* conv_b  = (const float*)d_in[8];
    const float* fc_w    = (const float*)d_in[9];
    const float* fc_b    = (const float*)d_in[10];
    float* out = (float*)d_out;

    // Workspace (~26 MB, no aliasing).
    float* xw1    = (float*)d_ws;                   // 1,280,000 f
    float* bufB   = xw1 + N_NODES * CH;             // 1,280,000 f  (h1, then h2)
    float* xw2    = bufB + N_NODES * CH;            // 1,280,000 f
    int2*  erec   = (int2*)(xw2 + N_NODES * CH);    // 640,000 x 8B
    int*   hist   = (int*)(erec + N_EDGES);         // NHB*10,000 i
    int*   chunks = hist + NHB * N_NODES;           // NCHUNK*NHB i
    int*   offs   = chunks + NCHUNK * NHB;          // 10,001 i
    float* dinv   = (float*)(offs + N_NODES + 1);   // 10,000 f
    float* vbuf   = dinv + N_NODES;                 // 384 f
    float* c0     = vbuf + 384;                     // 1 f

    // --- launch 1: count-hist || gemm1 || conv-fold ---
    build1_kernel<<<NHB + GT + 1, 256, 0, stream>>>(x, ei, W1, conv_w, conv_b,
                                                    fc_w, fc_b, xw1, hist,
                                                    chunks, vbuf, c0);
    // --- launch 2: prefix + cursor conversion ---
    reducebofs_kernel<<<NCHUNK, 256, 0, stream>>>(hist, chunks, offs);
    // --- launch 3: scatter {src, raw_w} into CSR order ---
    scatter_kernel<<<NHB, 256, 0, stream>>>(ei, ew, hist, erec);
    // --- launch 4: weighted degree -> dinv ---
    degdinv_kernel<<<N_NODES / 16, 256, 0, stream>>>(erec, offs, dinv);
    // --- launch 5: layer-1 aggregation ---
    agg_kernel<<<N_NODES / 8, 256, 0, stream>>>((const float4*)xw1, erec, offs,
                                                dinv, (const float4*)b1, (float4*)bufB);
    // --- launch 6: gemm2 ---
    gemm128_kernel<<<GT, 256, 0, stream>>>(bufB, W2, xw2);
    // --- launch 7: layer-2 aggregation ---
    agg_kernel<<<N_NODES / 8, 256, 0, stream>>>((const float4*)xw2, erec, offs,
                                                dinv, (const float4*)b2, (float4*)bufB);
    // --- launch 8: fused temporal conv + fc ---
    convfc_kernel<<<N_NODES / 8, 256, 0, stream>>>((const float4*)bufB, vbuf, c0, out);
}